// Round 1
// baseline (40.369 us; speedup 1.0000x reference)
//
#include <hip/hip_runtime.h>
#include <math.h>

#define CIN  64
#define HH   32
#define WW   32
#define OCH  64
#define IKK  576
#define DH   32
#define OIKK 36864

__device__ __forceinline__ float silu_f(float v) {
    return v / (1.0f + expf(-v));
}

// K1: h[b][pm][j] = silu(feat @ w1 + b1); feat = [pm//32/32, pm%32/32, c[b,:8]]
__global__ void k_mlp(const float* __restrict__ c, const float* __restrict__ w1,
                      const float* __restrict__ b1, float* __restrict__ h_ws) {
    int tid = blockIdx.x * blockDim.x + threadIdx.x;  // < 65536
    int b   = tid >> 15;
    int rem = tid & 32767;
    int pm  = rem >> 5;
    int j   = rem & 31;
    float f0 = (float)(pm >> 5) * (1.0f / 32.0f);
    float f1 = (float)(pm & 31) * (1.0f / 32.0f);
    float acc = b1[j];
    acc = fmaf(f0, w1[0 * DH + j], acc);
    acc = fmaf(f1, w1[1 * DH + j], acc);
    #pragma unroll
    for (int i = 0; i < 8; ++i)
        acc = fmaf(c[b * 8 + i], w1[(2 + i) * DH + j], acc);
    h_ws[tid] = silu_f(acc);
}

// K2: per (b,q) block: t[b,p,j], s[b,p] for the 16 pixels p = 64*pix + q.
//   t[b,p,j] = sum_ikk patch[pix][ikk] * w2[j][q*576+ikk]
//   s[b,p]   = sum_ikk patch[pix][ikk] * b2[q*576+ikk]
__global__ void k_ts(const float* __restrict__ x, const float* __restrict__ w2,
                     const float* __restrict__ b2, float* __restrict__ t_ws,
                     float* __restrict__ s_ws) {
    __shared__ float patch[16][580];   // [pix][ikk], stride 580 (row base 16B aligned)
    __shared__ float spart[16][8];
    int b   = blockIdx.x >> 6;
    int q   = blockIdx.x & 63;
    int par = q >> 5, xq = q & 31;
    int tid = threadIdx.x;

    // stage the 16 patches (pixels y = par+2*pix, x = xq)
    for (int idx = tid; idx < 16 * IKK; idx += 256) {
        int pix = idx / IKK;
        int ikk = idx - pix * IKK;
        int ci  = ikk / 9;
        int r   = ikk - ci * 9;
        int kh  = r / 3;
        int kw  = r - kh * 3;
        int yy  = par + 2 * pix + kh - 1;
        int xx  = xq + kw - 1;
        float v = 0.0f;
        if (yy >= 0 && yy < HH && xx >= 0 && xx < WW)
            v = x[((b * CIN + ci) * HH + yy) * WW + xx];
        patch[pix][ikk] = v;
    }
    __syncthreads();

    int j  = tid >> 3;   // 0..31
    int pg = tid & 7;    // pixels pg, pg+8
    const float4* wr  = (const float4*)(w2 + (size_t)j * OIKK + q * IKK);
    const float4* p0r = (const float4*)(&patch[pg][0]);
    const float4* p1r = (const float4*)(&patch[pg + 8][0]);
    float4 a0 = {0.f, 0.f, 0.f, 0.f}, a1 = {0.f, 0.f, 0.f, 0.f};
    #pragma unroll 4
    for (int k4 = 0; k4 < IKK / 4; ++k4) {
        float4 w = wr[k4];
        float4 u = p0r[k4];
        float4 v = p1r[k4];
        a0.x = fmaf(w.x, u.x, a0.x); a0.y = fmaf(w.y, u.y, a0.y);
        a0.z = fmaf(w.z, u.z, a0.z); a0.w = fmaf(w.w, u.w, a0.w);
        a1.x = fmaf(w.x, v.x, a1.x); a1.y = fmaf(w.y, v.y, a1.y);
        a1.z = fmaf(w.z, v.z, a1.z); a1.w = fmaf(w.w, v.w, a1.w);
    }
    float t0 = (a0.x + a0.y) + (a0.z + a0.w);
    float t1 = (a1.x + a1.y) + (a1.z + a1.w);
    int p0 = (pg << 6) + q;
    int p1 = ((pg + 8) << 6) + q;
    t_ws[(size_t)((b << 10) + p0) * DH + j] = t0;
    t_ws[(size_t)((b << 10) + p1) * DH + j] = t1;

    // s: 16 pixels x 8 K-chunks of 72
    if (tid < 128) {
        int pix = tid >> 3, kc = tid & 7;
        const float* b2q = b2 + q * IKK;
        float acc = 0.f;
        int k0 = kc * 72;
        #pragma unroll 8
        for (int ikk = k0; ikk < k0 + 72; ++ikk)
            acc = fmaf(patch[pix][ikk], b2q[ikk], acc);
        spart[pix][kc] = acc;
    }
    __syncthreads();
    if (tid < 16) {
        float acc = 0.f;
        #pragma unroll
        for (int kc = 0; kc < 8; ++kc) acc += spart[tid][kc];
        s_ws[(b << 10) + (tid << 6) + q] = acc;
    }
}

// K3: out[b,o,y,x] = static_conv + sum_j h[b,16o+y/2][j]*t[b,p,j] + s[b,p] + bias[o]
//   grid block = (b, y, oc): 16 output channels per block, 32 pixels (one row)
__global__ void k_out(const float* __restrict__ x, const float* __restrict__ kern,
                      const float* __restrict__ bias, const float* __restrict__ h_ws,
                      const float* __restrict__ t_ws, const float* __restrict__ s_ws,
                      float* __restrict__ out) {
    __shared__ float xs[CIN][3][34];   // x-padded slice rows y-1..y+1
    __shared__ float tl[32][33];       // t for this row's 32 pixels (+1 pad: bank)
    __shared__ float hl[16][33];
    __shared__ float sl[32];
    int bid = blockIdx.x;
    int b   = bid >> 7;
    int rem = bid & 127;
    int y   = rem >> 2;
    int oc  = rem & 3;
    int tid = threadIdx.x;

    for (int idx = tid; idx < CIN * 3 * 34; idx += 256) {
        int ci = idx / 102;
        int r  = idx - ci * 102;
        int kh = r / 34;
        int xx = r - kh * 34;
        int yy = y + kh - 1;
        int xc = xx - 1;
        float v = 0.0f;
        if (yy >= 0 && yy < HH && xc >= 0 && xc < WW)
            v = x[((b * CIN + ci) * HH + yy) * WW + xc];
        xs[ci][kh][xx] = v;
    }
    for (int idx = tid; idx < 1024; idx += 256) {
        int pix = idx >> 5, j = idx & 31;
        tl[pix][j] = t_ws[(size_t)((b << 10) + (y << 5) + pix) * DH + j];
    }
    for (int idx = tid; idx < 512; idx += 256) {
        int ol = idx >> 5, j = idx & 31;
        int o  = (oc << 4) + ol;
        hl[ol][j] = h_ws[(size_t)((b << 10) + (o << 4) + (y >> 1)) * DH + j];
    }
    if (tid < 32) sl[tid] = s_ws[(b << 10) + (y << 5) + tid];
    __syncthreads();

    int ol = tid >> 4;   // 0..15
    int xg = tid & 15;   // pixels xg, xg+16
    int o  = (oc << 4) + ol;
    const float* kr = kern + o * IKK;
    float acc0 = 0.f, acc1 = 0.f;
    for (int ci = 0; ci < CIN; ++ci) {
        #pragma unroll
        for (int kh = 0; kh < 3; ++kh) {
            float k0 = kr[ci * 9 + kh * 3 + 0];
            float k1 = kr[ci * 9 + kh * 3 + 1];
            float k2 = kr[ci * 9 + kh * 3 + 2];
            float a0 = xs[ci][kh][xg + 0];
            float a1 = xs[ci][kh][xg + 1];
            float a2 = xs[ci][kh][xg + 2];
            float c0 = xs[ci][kh][xg + 16];
            float c1 = xs[ci][kh][xg + 17];
            float c2 = xs[ci][kh][xg + 18];
            acc0 = fmaf(k0, a0, acc0); acc0 = fmaf(k1, a1, acc0); acc0 = fmaf(k2, a2, acc0);
            acc1 = fmaf(k0, c0, acc1); acc1 = fmaf(k1, c1, acc1); acc1 = fmaf(k2, c2, acc1);
        }
    }
    #pragma unroll 8
    for (int jj = 0; jj < DH; ++jj) {
        float hv = hl[ol][jj];
        acc0 = fmaf(hv, tl[xg][jj], acc0);
        acc1 = fmaf(hv, tl[xg + 16][jj], acc1);
    }
    float bo = bias[o];
    int base = ((b * OCH + o) << 10) + (y << 5);
    out[base + xg]      = acc0 + bo + sl[xg];
    out[base + xg + 16] = acc1 + bo + sl[xg + 16];
}

extern "C" void kernel_launch(void* const* d_in, const int* in_sizes, int n_in,
                              void* d_out, int out_size, void* d_ws, size_t ws_size,
                              hipStream_t stream) {
    const float* x    = (const float*)d_in[0];
    const float* c    = (const float*)d_in[1];
    const float* kern = (const float*)d_in[2];
    const float* bias = (const float*)d_in[3];
    const float* w1   = (const float*)d_in[4];
    const float* b1   = (const float*)d_in[5];
    const float* w2   = (const float*)d_in[6];
    const float* b2   = (const float*)d_in[7];
    float* out  = (float*)d_out;
    float* h_ws = (float*)d_ws;         // 65536 floats
    float* t_ws = h_ws + 65536;         // 65536 floats
    float* s_ws = t_ws + 65536;         // 2048 floats

    k_mlp<<<256, 256, 0, stream>>>(c, w1, b1, h_ws);
    k_ts <<<128, 256, 0, stream>>>(x, w2, b2, t_ws, s_ws);
    k_out<<<256, 256, 0, stream>>>(x, kern, bias, h_ws, t_ws, s_ws, out);
}

// Round 3
// 27.996 us; speedup vs baseline: 1.4420x; 1.4420x over previous
//
#include <hip/hip_runtime.h>
#include <math.h>

#define CIN  64
#define HH   32
#define WW   32
#define OCH  64
#define IKK  576
#define DH   32
#define OIKK 36864

__device__ __forceinline__ float silu_f(float v) {
    return v / (1.0f + __expf(-v));
}

// K_ts: block=(b,q,ph): t[b,j,p] and s[b,p] for 8 pixels p=(ph*8+pg)*64+q.
//   t = patch . w2[j][q*576+:], s = patch . b2[q*576+:]
//   threads (kq4, jg8, pg8): 4-way K-split, 4 j's per thread, 1 pixel.
__global__ __launch_bounds__(256) void k_ts(const float* __restrict__ x,
                                            const float* __restrict__ w2,
                                            const float* __restrict__ b2,
                                            float* __restrict__ t_ws,
                                            float* __restrict__ s_ws) {
    __shared__ float patch[8][584];      // row stride 584 floats (16B-mult, 2-way banks)
    __shared__ float red[4][8][4][8];    // [kq][jg][jj][pg]
    __shared__ float spart[8][32];
    int bid = blockIdx.x;
    int b   = bid >> 7;
    int q   = (bid >> 1) & 63;
    int ph  = bid & 1;
    int par = q >> 5, xq = q & 31;
    int tid = threadIdx.x;

    // stage 8 patches (pixels y = 2*(ph*8+pix)+par, x = xq)
    for (int idx = tid; idx < 8 * IKK; idx += 256) {
        int pix = idx / IKK;
        int ikk = idx - pix * IKK;
        int ci  = ikk / 9;
        int r   = ikk - ci * 9;
        int kh  = r / 3;
        int kw  = r - kh * 3;
        int yy  = 2 * (ph * 8 + pix) + par + kh - 1;
        int xx  = xq + kw - 1;
        float v = 0.0f;
        if (yy >= 0 && yy < HH && xx >= 0 && xx < WW)
            v = x[((b * CIN + ci) * HH + yy) * WW + xx];
        patch[pix][ikk] = v;
    }
    __syncthreads();

    int kq = tid >> 6;          // 0..3 (wave-uniform)
    int jg = (tid >> 3) & 7;    // 0..7 -> j = jg*4+jj
    int pg = tid & 7;           // pixel within block
    const float4* pr  = (const float4*)(&patch[pg][0]) + kq * 36;
    const float4* wp0 = (const float4*)(w2 + (size_t)(jg * 4 + 0) * OIKK + q * IKK) + kq * 36;
    const float4* wp1 = (const float4*)(w2 + (size_t)(jg * 4 + 1) * OIKK + q * IKK) + kq * 36;
    const float4* wp2 = (const float4*)(w2 + (size_t)(jg * 4 + 2) * OIKK + q * IKK) + kq * 36;
    const float4* wp3 = (const float4*)(w2 + (size_t)(jg * 4 + 3) * OIKK + q * IKK) + kq * 36;
    float4 a0 = {0,0,0,0}, a1 = {0,0,0,0}, a2 = {0,0,0,0}, a3 = {0,0,0,0};
    #pragma unroll 4
    for (int it = 0; it < 36; ++it) {
        float4 pv = pr[it];
        float4 w0 = wp0[it], w1v = wp1[it], w2v = wp2[it], w3v = wp3[it];
        a0.x = fmaf(w0.x, pv.x, a0.x); a0.y = fmaf(w0.y, pv.y, a0.y);
        a0.z = fmaf(w0.z, pv.z, a0.z); a0.w = fmaf(w0.w, pv.w, a0.w);
        a1.x = fmaf(w1v.x, pv.x, a1.x); a1.y = fmaf(w1v.y, pv.y, a1.y);
        a1.z = fmaf(w1v.z, pv.z, a1.z); a1.w = fmaf(w1v.w, pv.w, a1.w);
        a2.x = fmaf(w2v.x, pv.x, a2.x); a2.y = fmaf(w2v.y, pv.y, a2.y);
        a2.z = fmaf(w2v.z, pv.z, a2.z); a2.w = fmaf(w2v.w, pv.w, a2.w);
        a3.x = fmaf(w3v.x, pv.x, a3.x); a3.y = fmaf(w3v.y, pv.y, a3.y);
        a3.z = fmaf(w3v.z, pv.z, a3.z); a3.w = fmaf(w3v.w, pv.w, a3.w);
    }
    red[kq][jg][0][pg] = (a0.x + a0.y) + (a0.z + a0.w);
    red[kq][jg][1][pg] = (a1.x + a1.y) + (a1.z + a1.w);
    red[kq][jg][2][pg] = (a2.x + a2.y) + (a2.z + a2.w);
    red[kq][jg][3][pg] = (a3.x + a3.y) + (a3.z + a3.w);
    __syncthreads();

    // t reduce across kq + write (transposed layout t_ws[b][j][p])
    {
        int j = tid >> 3, pgr = tid & 7;
        int jg2 = j >> 2, jj2 = j & 3;
        float sum = (red[0][jg2][jj2][pgr] + red[1][jg2][jj2][pgr])
                  + (red[2][jg2][jj2][pgr] + red[3][jg2][jj2][pgr]);
        int p = ((ph << 3) + pgr) * 64 + q;
        t_ws[(size_t)b * 32768 + (size_t)j * 1024 + p] = sum;
    }
    // s partials: (pix8 x kc32), 18 elems each
    {
        int pix = tid >> 5, kc = tid & 31;
        const float* b2q = b2 + q * IKK + kc * 18;
        const float* pp  = &patch[pix][kc * 18];
        float acc = 0.f;
        #pragma unroll
        for (int i2 = 0; i2 < 18; ++i2) acc = fmaf(pp[i2], b2q[i2], acc);
        spart[pix][kc] = acc;
    }
    __syncthreads();
    if (tid < 8) {
        float acc = 0.f;
        #pragma unroll
        for (int kc = 0; kc < 32; ++kc) acc += spart[tid][kc];
        s_ws[(b << 10) + ((ph << 3) + tid) * 64 + q] = acc;
    }
}

// K_out: block=(b,y,oc): 16 o x 32 pixels (one row). 128 threads.
//   thread (ol8, xg16): o in {oc*16+ol, +8}, pixels {2xg, 2xg+1}.
//   out = conv(kern) + sum_j h[o][j]*t[j][pix] + s[pix] + bias[o]
__global__ __launch_bounds__(128) void k_out(const float* __restrict__ x,
                                             const float* __restrict__ kern,
                                             const float* __restrict__ bias,
                                             const float* __restrict__ c,
                                             const float* __restrict__ w1,
                                             const float* __restrict__ b1,
                                             const float* __restrict__ t_ws,
                                             const float* __restrict__ s_ws,
                                             float* __restrict__ out) {
    __shared__ float xs[CIN][3][36];   // left-padded rows: xs[ci][kh][1+i] = x[i]
    __shared__ float tl[DH][36];       // transposed t: [j][pix]
    __shared__ float hl[16][33];
    __shared__ float sl[32];
    int bid = blockIdx.x;
    int b   = bid >> 7;
    int y   = (bid >> 2) & 31;
    int oc  = bid & 3;
    int tid = threadIdx.x;

    // xs staging: one full padded row per iteration, float4 loads + shifted stores
    for (int r = tid; r < 192; r += 128) {
        int ci = r / 3;
        int kh = r - ci * 3;
        int yy = y + kh - 1;
        float4* dst = (float4*)(&xs[ci][kh][0]);
        if (yy >= 0 && yy < HH) {
            const float4* src = (const float4*)(x + ((b * CIN + ci) * HH + yy) * WW);
            float4 v[8];
            #pragma unroll
            for (int j = 0; j < 8; ++j) v[j] = src[j];
            dst[0] = make_float4(0.f, v[0].x, v[0].y, v[0].z);
            #pragma unroll
            for (int j = 1; j < 8; ++j)
                dst[j] = make_float4(v[j - 1].w, v[j].x, v[j].y, v[j].z);
            dst[8] = make_float4(v[7].w, 0.f, 0.f, 0.f);
        } else {
            float4 z = {0.f, 0.f, 0.f, 0.f};
            #pragma unroll
            for (int j = 0; j < 9; ++j) dst[j] = z;
        }
    }
    // tl staging (t_ws[b][j][p] rows are contiguous in p)
    for (int idx = tid; idx < 256; idx += 128) {
        int j = idx >> 3, g = idx & 7;
        float4 v = *(const float4*)(t_ws + (size_t)b * 32768 + (size_t)j * 1024 + (y << 5) + (g << 2));
        *((float4*)(&tl[j][0]) + g) = v;
    }
    // hl: inline MLP h = silu(feat @ w1 + b1), pm = o*16 + y/2
    for (int idx = tid; idx < 512; idx += 128) {
        int olx = idx >> 5, j = idx & 31;
        int o   = (oc << 4) + olx;
        int pm  = (o << 4) + (y >> 1);
        float f0 = (float)(pm >> 5) * (1.0f / 32.0f);
        float f1 = (float)(pm & 31) * (1.0f / 32.0f);
        float acc = b1[j];
        acc = fmaf(f0, w1[j], acc);
        acc = fmaf(f1, w1[DH + j], acc);
        #pragma unroll
        for (int i = 0; i < 8; ++i)
            acc = fmaf(c[(b << 3) + i], w1[(2 + i) * DH + j], acc);
        hl[olx][j] = silu_f(acc);
    }
    if (tid < 32) sl[tid] = s_ws[(b << 10) + (y << 5) + tid];
    __syncthreads();

    int ol = tid >> 4;   // 0..7
    int xg = tid & 15;   // pixel pair 2xg, 2xg+1
    int o0 = (oc << 4) + ol;
    int o1 = o0 + 8;
    const float4* k0p = (const float4*)(kern + o0 * IKK);
    const float4* k1p = (const float4*)(kern + o1 * IKK);
    float acc00 = 0.f, acc01 = 0.f, acc10 = 0.f, acc11 = 0.f;

    for (int cb = 0; cb < 16; ++cb) {        // 4 ci per block
        float ka[36], kb[36];
        #pragma unroll
        for (int rr = 0; rr < 9; ++rr) {
            float4 va = k0p[cb * 9 + rr];
            ka[rr * 4 + 0] = va.x; ka[rr * 4 + 1] = va.y;
            ka[rr * 4 + 2] = va.z; ka[rr * 4 + 3] = va.w;
            float4 vb = k1p[cb * 9 + rr];
            kb[rr * 4 + 0] = vb.x; kb[rr * 4 + 1] = vb.y;
            kb[rr * 4 + 2] = vb.z; kb[rr * 4 + 3] = vb.w;
        }
        #pragma unroll
        for (int i = 0; i < 4; ++i) {
            int ci = (cb << 2) + i;
            #pragma unroll
            for (int kh = 0; kh < 3; ++kh) {
                const float* row = &xs[ci][kh][0];
                float2 fA = *(const float2*)(row + 2 * xg);
                float2 fB = *(const float2*)(row + 2 * xg + 2);
                int e = i * 9 + kh * 3;
                float k0a = ka[e], k1a = ka[e + 1], k2a = ka[e + 2];
                float k0b = kb[e], k1b = kb[e + 1], k2b = kb[e + 2];
                acc00 = fmaf(k0a, fA.x, acc00);
                acc00 = fmaf(k1a, fA.y, acc00);
                acc00 = fmaf(k2a, fB.x, acc00);
                acc01 = fmaf(k0a, fA.y, acc01);
                acc01 = fmaf(k1a, fB.x, acc01);
                acc01 = fmaf(k2a, fB.y, acc01);
                acc10 = fmaf(k0b, fA.x, acc10);
                acc10 = fmaf(k1b, fA.y, acc10);
                acc10 = fmaf(k2b, fB.x, acc10);
                acc11 = fmaf(k0b, fA.y, acc11);
                acc11 = fmaf(k1b, fB.x, acc11);
                acc11 = fmaf(k2b, fB.y, acc11);
            }
        }
    }
    // dynamic part: acc += h[o][j] * t[j][pix]
    #pragma unroll 8
    for (int jj = 0; jj < DH; ++jj) {
        float2 tv = *(const float2*)(&tl[jj][2 * xg]);
        float h0 = hl[ol][jj];
        float h1 = hl[ol + 8][jj];
        acc00 = fmaf(h0, tv.x, acc00);
        acc01 = fmaf(h0, tv.y, acc01);
        acc10 = fmaf(h1, tv.x, acc10);
        acc11 = fmaf(h1, tv.y, acc11);
    }
    float bo0 = bias[o0], bo1 = bias[o1];
    float s0 = sl[2 * xg], s1 = sl[2 * xg + 1];
    int base0 = ((b * OCH + o0) << 10) + (y << 5) + 2 * xg;
    int base1 = ((b * OCH + o1) << 10) + (y << 5) + 2 * xg;
    *(float2*)(out + base0) = make_float2(acc00 + bo0 + s0, acc01 + bo0 + s1);
    *(float2*)(out + base1) = make_float2(acc10 + bo1 + s0, acc11 + bo1 + s1);
}

extern "C" void kernel_launch(void* const* d_in, const int* in_sizes, int n_in,
                              void* d_out, int out_size, void* d_ws, size_t ws_size,
                              hipStream_t stream) {
    const float* x    = (const float*)d_in[0];
    const float* c    = (const float*)d_in[1];
    const float* kern = (const float*)d_in[2];
    const float* bias = (const float*)d_in[3];
    const float* w1   = (const float*)d_in[4];
    const float* b1   = (const float*)d_in[5];
    const float* w2   = (const float*)d_in[6];
    const float* b2   = (const float*)d_in[7];
    float* out  = (float*)d_out;
    float* t_ws = (float*)d_ws;         // 65536 floats, layout [b][j][p]
    float* s_ws = t_ws + 65536;         // 2048 floats,  layout [b][p]

    k_ts <<<256, 256, 0, stream>>>(x, w2, b2, t_ws, s_ws);
    k_out<<<256, 128, 0, stream>>>(x, kern, bias, c, w1, b1, t_ws, s_ws, out);
}

// Round 8
// 22.258 us; speedup vs baseline: 1.8137x; 1.2578x over previous
//
#include <hip/hip_runtime.h>
#include <math.h>

#define CIN  64
#define HH   32
#define WW   32
#define OCH  64
#define IKK  576
#define DH   32
#define OIKK 36864

__device__ __forceinline__ float silu_f(float v) {
    return v / (1.0f + __expf(-v));
}

// K_ts: block=(b,q,ph): t[b,j,p], s[b,p] for 4 pixels p=(ph*4+pg)*64+q.
//   threads (kq8, jg8, pg4): 8-way K-split (72 floats), 4 j's, 1 pixel.
//   grid 512 -> 2 blocks/CU.
__global__ __launch_bounds__(256) void k_ts(const float* __restrict__ x,
                                            const float* __restrict__ w2,
                                            const float* __restrict__ b2,
                                            float* __restrict__ t_ws,
                                            float* __restrict__ s_ws) {
    __shared__ float patch[4][584];      // row stride 584 (2336B, 16B-mult)
    __shared__ float red[8][8][4][4];    // [kq][jg][jj][pg]
    __shared__ float spart[4][64];
    int bid = blockIdx.x;
    int b   = bid >> 8;
    int q   = (bid >> 2) & 63;
    int ph  = bid & 3;
    int par = q >> 5, xq = q & 31;
    int tid = threadIdx.x;

    // stage 4 patches (pixels y = 2*(ph*4+pgi)+par, x = xq); 9 elems/thread
    for (int idx = tid; idx < 4 * IKK; idx += 256) {
        int pgi = idx / IKK;
        int ikk = idx - pgi * IKK;
        int ci  = ikk / 9;
        int r   = ikk - ci * 9;
        int kh  = r / 3;
        int kw  = r - kh * 3;
        int yy  = 2 * (ph * 4 + pgi) + par + kh - 1;
        int xx  = xq + kw - 1;
        float v = 0.0f;
        if (yy >= 0 && yy < HH && xx >= 0 && xx < WW)
            v = x[((b * CIN + ci) * HH + yy) * WW + xx];
        patch[pgi][ikk] = v;
    }
    __syncthreads();

    int kq = tid >> 5;          // 0..7
    int jg = (tid >> 2) & 7;    // 0..7
    int pg = tid & 3;           // 0..3
    const float4* pr  = (const float4*)(&patch[pg][0]) + kq * 18;
    const float4* wp0 = (const float4*)(w2 + (size_t)(jg * 4 + 0) * OIKK + q * IKK) + kq * 18;
    const float4* wp1 = (const float4*)(w2 + (size_t)(jg * 4 + 1) * OIKK + q * IKK) + kq * 18;
    const float4* wp2 = (const float4*)(w2 + (size_t)(jg * 4 + 2) * OIKK + q * IKK) + kq * 18;
    const float4* wp3 = (const float4*)(w2 + (size_t)(jg * 4 + 3) * OIKK + q * IKK) + kq * 18;
    float4 a0 = {0,0,0,0}, a1 = {0,0,0,0}, a2 = {0,0,0,0}, a3 = {0,0,0,0};
    #pragma unroll 6
    for (int it = 0; it < 18; ++it) {
        float4 pv = pr[it];
        float4 w0 = wp0[it], w1v = wp1[it], w2v = wp2[it], w3v = wp3[it];
        a0.x = fmaf(w0.x, pv.x, a0.x); a0.y = fmaf(w0.y, pv.y, a0.y);
        a0.z = fmaf(w0.z, pv.z, a0.z); a0.w = fmaf(w0.w, pv.w, a0.w);
        a1.x = fmaf(w1v.x, pv.x, a1.x); a1.y = fmaf(w1v.y, pv.y, a1.y);
        a1.z = fmaf(w1v.z, pv.z, a1.z); a1.w = fmaf(w1v.w, pv.w, a1.w);
        a2.x = fmaf(w2v.x, pv.x, a2.x); a2.y = fmaf(w2v.y, pv.y, a2.y);
        a2.z = fmaf(w2v.z, pv.z, a2.z); a2.w = fmaf(w2v.w, pv.w, a2.w);
        a3.x = fmaf(w3v.x, pv.x, a3.x); a3.y = fmaf(w3v.y, pv.y, a3.y);
        a3.z = fmaf(w3v.z, pv.z, a3.z); a3.w = fmaf(w3v.w, pv.w, a3.w);
    }
    red[kq][jg][0][pg] = (a0.x + a0.y) + (a0.z + a0.w);
    red[kq][jg][1][pg] = (a1.x + a1.y) + (a1.z + a1.w);
    red[kq][jg][2][pg] = (a2.x + a2.y) + (a2.z + a2.w);
    red[kq][jg][3][pg] = (a3.x + a3.y) + (a3.z + a3.w);

    // s partials: (pix4 x kc64), 9 elems each (reads patch, no barrier needed yet)
    {
        int pix = tid >> 6, kc = tid & 63;
        const float* b2q = b2 + q * IKK + kc * 9;
        const float* pp  = &patch[pix][kc * 9];
        float acc = 0.f;
        #pragma unroll
        for (int i2 = 0; i2 < 9; ++i2) acc = fmaf(pp[i2], b2q[i2], acc);
        spart[pix][kc] = acc;
    }
    __syncthreads();

    // t reduce over kq + write (layout t_ws[b][j][p])
    if (tid < 128) {
        int j = tid >> 2, pg2 = tid & 3;
        int jg2 = j >> 2, jj2 = j & 3;
        float sum = 0.f;
        #pragma unroll
        for (int k = 0; k < 8; ++k) sum += red[k][jg2][jj2][pg2];
        int p = ((ph << 2) + pg2) * 64 + q;
        t_ws[(size_t)b * 32768 + (size_t)j * 1024 + p] = sum;
    }
    if (tid < 4) {
        float acc = 0.f;
        #pragma unroll
        for (int kc = 0; kc < 64; ++kc) acc += spart[tid][kc];
        s_ws[(b << 10) + ((ph << 2) + tid) * 64 + q] = acc;
    }
}

// K_out: block=(b,y,oc): 16 o x 32 px (one row). 256 threads = (cq4, ol8, xg8).
//   Phase A: thread = 2 o (ol, ol+8) x 4 px (4xg..4xg+3) x 16 ci (cq slice).
//   Phase B: thread = (ou16, xp16): gather psum over cq + dyn h.t + write.
__global__ __launch_bounds__(256) void k_out(const float* __restrict__ x,
                                             const float* __restrict__ kern,
                                             const float* __restrict__ bias,
                                             const float* __restrict__ c,
                                             const float* __restrict__ w1,
                                             const float* __restrict__ b1,
                                             const float* __restrict__ t_ws,
                                             const float* __restrict__ s_ws,
                                             float* __restrict__ out) {
    __shared__ __align__(16) float xs[CIN][3][36];   // left-pad: xs[ci][kh][1+i]=x[i]
    __shared__ __align__(16) float tl[DH][36];       // [j][px]
    __shared__ float hl[16][33];
    __shared__ float sl[32];
    __shared__ float psum[2560];                     // [tid][10] padded
    int bid = blockIdx.x;
    int b   = bid >> 7;
    int y   = (bid >> 2) & 31;
    int oc  = bid & 3;
    int tid = threadIdx.x;

    // xs staging: 192 padded rows, float4 loads + shifted stores
    if (tid < 192) {
        int ci = tid / 3;
        int kh = tid - ci * 3;
        int yy = y + kh - 1;
        float4* dst = (float4*)(&xs[ci][kh][0]);
        if (yy >= 0 && yy < HH) {
            const float4* src = (const float4*)(x + ((b * CIN + ci) * HH + yy) * WW);
            float4 v[8];
            #pragma unroll
            for (int j = 0; j < 8; ++j) v[j] = src[j];
            dst[0] = make_float4(0.f, v[0].x, v[0].y, v[0].z);
            #pragma unroll
            for (int j = 1; j < 8; ++j)
                dst[j] = make_float4(v[j - 1].w, v[j].x, v[j].y, v[j].z);
            dst[8] = make_float4(v[7].w, 0.f, 0.f, 0.f);
        } else {
            float4 z = {0.f, 0.f, 0.f, 0.f};
            #pragma unroll
            for (int j = 0; j < 9; ++j) dst[j] = z;
        }
    }
    // tl: t row (stride 36 -> 16B-aligned float4 stores)
    if (tid < 256) {
        int j = tid >> 3, g = tid & 7;
        float4 v = *(const float4*)(t_ws + (size_t)b * 32768 + (size_t)j * 1024 + (y << 5) + (g << 2));
        *(float4*)(&tl[j][g << 2]) = v;
    }
    // hl: inline MLP, pm = o*16 + y/2
    for (int idx = tid; idx < 512; idx += 256) {
        int olx = idx >> 5, j = idx & 31;
        int o   = (oc << 4) + olx;
        int pm  = (o << 4) + (y >> 1);
        float f0 = (float)(pm >> 5) * (1.0f / 32.0f);
        float f1 = (float)(pm & 31) * (1.0f / 32.0f);
        float acc = b1[j];
        acc = fmaf(f0, w1[j], acc);
        acc = fmaf(f1, w1[DH + j], acc);
        #pragma unroll
        for (int i = 0; i < 8; ++i)
            acc = fmaf(c[(b << 3) + i], w1[(2 + i) * DH + j], acc);
        hl[olx][j] = silu_f(acc);
    }
    if (tid < 32) sl[tid] = s_ws[(b << 10) + (y << 5) + tid];
    __syncthreads();

    // ---- Phase A: conv partials over ci slice ----
    {
        int cq = tid >> 6;         // 0..3
        int ol = (tid >> 3) & 7;   // 0..7
        int xg = tid & 7;          // 0..7 -> px 4xg..4xg+3
        int o0 = (oc << 4) + ol;
        int o1 = o0 + 8;
        int ci0 = cq << 4;
        const float4* k0p = (const float4*)(kern + o0 * IKK + ci0 * 9);
        const float4* k1p = (const float4*)(kern + o1 * IKK + ci0 * 9);
        float aA[4] = {0.f, 0.f, 0.f, 0.f};   // o0, px 0..3
        float aB[4] = {0.f, 0.f, 0.f, 0.f};   // o1
        for (int c4 = 0; c4 < 4; ++c4) {      // 4 ci per iter
            float ka[36], kb[36];
            #pragma unroll
            for (int rr = 0; rr < 9; ++rr) {
                float4 va = k0p[c4 * 9 + rr];
                ka[rr * 4 + 0] = va.x; ka[rr * 4 + 1] = va.y;
                ka[rr * 4 + 2] = va.z; ka[rr * 4 + 3] = va.w;
                float4 vb = k1p[c4 * 9 + rr];
                kb[rr * 4 + 0] = vb.x; kb[rr * 4 + 1] = vb.y;
                kb[rr * 4 + 2] = vb.z; kb[rr * 4 + 3] = vb.w;
            }
            #pragma unroll
            for (int i = 0; i < 4; ++i) {
                int ci = ci0 + (c4 << 2) + i;
                #pragma unroll
                for (int kh = 0; kh < 3; ++kh) {
                    const float* row = &xs[ci][kh][0];
                    float4 v4 = *(const float4*)(row + 4 * xg);
                    float2 v2 = *(const float2*)(row + 4 * xg + 4);
                    int e = i * 9 + kh * 3;
                    float k0a = ka[e], k1a = ka[e + 1], k2a = ka[e + 2];
                    float k0b = kb[e], k1b = kb[e + 1], k2b = kb[e + 2];
                    aA[0] = fmaf(k0a, v4.x, aA[0]); aA[0] = fmaf(k1a, v4.y, aA[0]); aA[0] = fmaf(k2a, v4.z, aA[0]);
                    aA[1] = fmaf(k0a, v4.y, aA[1]); aA[1] = fmaf(k1a, v4.z, aA[1]); aA[1] = fmaf(k2a, v4.w, aA[1]);
                    aA[2] = fmaf(k0a, v4.z, aA[2]); aA[2] = fmaf(k1a, v4.w, aA[2]); aA[2] = fmaf(k2a, v2.x, aA[2]);
                    aA[3] = fmaf(k0a, v4.w, aA[3]); aA[3] = fmaf(k1a, v2.x, aA[3]); aA[3] = fmaf(k2a, v2.y, aA[3]);
                    aB[0] = fmaf(k0b, v4.x, aB[0]); aB[0] = fmaf(k1b, v4.y, aB[0]); aB[0] = fmaf(k2b, v4.z, aB[0]);
                    aB[1] = fmaf(k0b, v4.y, aB[1]); aB[1] = fmaf(k1b, v4.z, aB[1]); aB[1] = fmaf(k2b, v4.w, aB[1]);
                    aB[2] = fmaf(k0b, v4.z, aB[2]); aB[2] = fmaf(k1b, v4.w, aB[2]); aB[2] = fmaf(k2b, v2.x, aB[2]);
                    aB[3] = fmaf(k0b, v4.w, aB[3]); aB[3] = fmaf(k1b, v2.x, aB[3]); aB[3] = fmaf(k2b, v2.y, aB[3]);
                }
            }
        }
        float2* sp = (float2*)(psum + tid * 10);
        sp[0] = make_float2(aA[0], aA[1]);
        sp[1] = make_float2(aA[2], aA[3]);
        sp[2] = make_float2(aB[0], aB[1]);
        sp[3] = make_float2(aB[2], aB[3]);
    }
    __syncthreads();

    // ---- Phase B: gather + dynamic part + write ----
    {
        int ou = tid >> 4;   // 0..15
        int xp = tid & 15;   // px pair 2xp, 2xp+1
        int o  = (oc << 4) + ou;
        int ol2 = ou & 7, oo = ou >> 3, xg2 = xp >> 1;
        int ppb = (xp & 1) << 1;
        float c0 = 0.f, c1 = 0.f;
        #pragma unroll
        for (int cq = 0; cq < 4; ++cq) {
            int t2 = (cq << 6) + (ol2 << 3) + xg2;
            float2 v = *(const float2*)(psum + t2 * 10 + (oo << 2) + ppb);
            c0 += v.x; c1 += v.y;
        }
        #pragma unroll 8
        for (int jj = 0; jj < DH; ++jj) {
            float2 tv = *(const float2*)(&tl[jj][2 * xp]);
            float hv = hl[ou][jj];
            c0 = fmaf(hv, tv.x, c0);
            c1 = fmaf(hv, tv.y, c1);
        }
        float bo = bias[o];
        int base = ((b * OCH + o) << 10) + (y << 5) + 2 * xp;
        *(float2*)(out + base) = make_float2(c0 + bo + sl[2 * xp], c1 + bo + sl[2 * xp + 1]);
    }
}

extern "C" void kernel_launch(void* const* d_in, const int* in_sizes, int n_in,
                              void* d_out, int out_size, void* d_ws, size_t ws_size,
                              hipStream_t stream) {
    const float* x    = (const float*)d_in[0];
    const float* c    = (const float*)d_in[1];
    const float* kern = (const float*)d_in[2];
    const float* bias = (const float*)d_in[3];
    const float* w1   = (const float*)d_in[4];
    const float* b1   = (const float*)d_in[5];
    const float* w2   = (const float*)d_in[6];
    const float* b2   = (const float*)d_in[7];
    float* out  = (float*)d_out;
    float* t_ws = (float*)d_ws;         // 65536 floats, [b][j][p]
    float* s_ws = t_ws + 65536;         // 2048 floats,  [b][p]

    k_ts <<<512, 256, 0, stream>>>(x, w2, b2, t_ws, s_ws);
    k_out<<<256, 256, 0, stream>>>(x, kern, bias, c, w1, b1, t_ws, s_ws, out);
}